// Round 4
// baseline (633.638 us; speedup 1.0000x reference)
//
#include <hip/hip_runtime.h>
#include <math.h>

#define D_DIM 128
#define H_DIM 256
#define W_DIM 256
#define HW (H_DIM * W_DIM)
#define HW4 (HW / 4)
#define NIMG 2
#define NPI (D_DIM * HW)
#define NTOT (NIMG * NPI)

#define TDZ 32
#define TH 8
#define TW 32

#define AW4 10     // aS row width in float4 (40 floats), window gx = x0-4 .. x0+35
#define AH 12      // aS rows, gy = y0-2 .. y0+9
#define MW4 9      // mWS/eT row width in float4 (36 cols), col j -> center gx = x0-2+j
#define EH 10      // eT rows, gy = y0-1+mh

#define NLOAD (AH * AW4)     // 120
#define NMINW (AH * MW4)     // 108
#define NMINH (EH * MW4)     // 90
#define NOUT  (TH * (TW/4))  // 64

#define NUM_ITER 20
#define STOP_THRESH 1e-4

__device__ __forceinline__ float min3f(float a, float b, float c) { return fminf(fminf(a, b), c); }
__device__ __forceinline__ float max3f(float a, float b, float c) { return fmaxf(fmaxf(a, b), c); }
__device__ __forceinline__ float leaky(float x) { return fmaxf(x, 0.01f * x); }

__global__ void init_slots(double* slots) {
    if (threadIdx.x < 32) slots[threadIdx.x] = 0.0;
}

// Fully float4-granular rolling-slice fused step:
//   e = minpool3^3(a_in) (+inf pad), a_out = e, d = maxpool3^3(e) (-inf pad),
//   delta = leaky(a_in - d), skel update + dn accumulation.
// minW: sliding-window min3 on f4 pairs; minH+D-min in rolling registers;
// max9 direct from eroded slice (6 b128 reads / 4 outputs).
__global__ __launch_bounds__(256) void skel_step(
    const float* __restrict__ a_in,
    float* __restrict__ a_out,
    float* __restrict__ skel,
    double* __restrict__ slots,
    int step)
{
    __shared__ float4 aS4[2][AH * AW4];   // ping-pong input window
    __shared__ float4 mWS4[AH * MW4];     // min over W
    __shared__ float4 eT4[EH * MW4];      // eroded slice (masked, halo 1)
    __shared__ float wsum[4];
    __shared__ int s_active;

    const int t = threadIdx.x;

    if (t == 0) {
        int act = 1;
        for (int j = 1; j < step; ++j)
            if (!(slots[j] >= STOP_THRESH * (double)NTOT)) { act = 0; break; }
        s_active = act;
    }
    __syncthreads();
    if (!s_active) return;

    const int bx = blockIdx.x, by = blockIdx.y;
    const int bz = blockIdx.z & 3, img = blockIdx.z >> 2;
    const int x0 = bx * TW, y0 = by * TH, z0 = bz * TDZ;

    const float* in = a_in + (size_t)img * NPI;
    float4* aout4 = (float4*)(a_out + (size_t)img * NPI);
    float4* sk4 = (float4*)(skel + (size_t)img * NPI);

    const int wv = t >> 6, ln = t & 63;
    const int g = ln * 4 + wv;            // spread across waves

    // ---- load role (plain t for coalescing) ----
    const bool isL = t < NLOAD;
    int lWr = 0, lOff = 0; bool lVal = false;
    {
        int lr = t / AW4, lc = t - lr * AW4;
        int gy = y0 - 2 + lr, gx = x0 - 4 + 4 * lc;
        lVal = ((unsigned)gy < H_DIM) && (gx >= 0) && (gx <= W_DIM - 4);
        lOff = gy * W_DIM + gx;
        lWr = lr * AW4 + lc;
    }

    // ---- minW role (stateless) ----
    const bool isW = g < NMINW;
    int wRd = 0, wWr = 0;
    {
        int gq = isW ? g : 0;
        int fh = gq / MW4, wj = gq - fh * MW4;
        wRd = fh * AW4 + wj;
        wWr = fh * MW4 + wj;
    }

    // ---- minH role (rolling f4 D-min state) ----
    const int ghi = g - 136;
    const bool isH = (ghi >= 0) && (ghi < NMINH);
    int hRd = 0, hWr = 0;
    bool sp0 = false, sp1 = false, sp2 = false, sp3 = false;
    {
        int gq = isH ? ghi : 0;
        int mh = gq / MW4, hj = gq - mh * MW4;
        hRd = mh * MW4 + hj;
        hWr = hRd;
        int gye = y0 - 1 + mh;
        bool gyok = (unsigned)gye < H_DIM;
        int gxb = x0 - 2 + 4 * hj;
        sp0 = gyok && ((unsigned)(gxb + 0) < W_DIM);
        sp1 = gyok && ((unsigned)(gxb + 1) < W_DIM);
        sp2 = gyok && ((unsigned)(gxb + 2) < W_DIM);
        sp3 = gyok && ((unsigned)(gxb + 3) < W_DIM);
    }

    // ---- output role (rolling max/ac/ec state) ----
    const int go = (g + 30) & 255;
    const bool isO = go < NOUT;
    int oRd = 0, oAc = 0;
    size_t ob = 0;
    {
        int gq = isO ? go : 0;
        int oh = gq >> 3, wq = gq & 7;
        oRd = oh * MW4 + wq;
        oAc = (oh + 2) * AW4 + wq + 1;
        ob = ((size_t)z0 * HW + (size_t)(y0 + oh) * W_DIM + (size_t)x0) / 4 + wq;
    }

    const float INF = INFINITY;
    float4 mP2 = make_float4(INF, INF, INF, INF), mP1 = mP2;
    float4 xP2 = make_float4(-INF, -INF, -INF, -INF), xP1 = xP2;
    float4 acA = make_float4(0, 0, 0, 0), acB = acA, ecA = acA;
    float lsum = 0.f;

    // initial prefetch: slice zl = z0-2
    float4 pf = make_float4(INF, INF, INF, INF);
    if (isL) {
        int z = z0 - 2;
        if ((unsigned)z < D_DIM && lVal)
            pf = *(const float4*)(in + (size_t)z * HW + lOff);
    }

    for (int i = 0; i < TDZ + 4; ++i) {
        const int cur = i & 1;

        // commit prefetched slice
        if (isL) aS4[cur][lWr] = pf;
        __syncthreads();   // B1: aS4[cur] ready

        // minW (sliding window) + issue next prefetch
        if (isW) {
            float4 a = aS4[cur][wRd];
            float4 b = aS4[cur][wRd + 1];
            float4 o;
            o.x = min3f(a.y, a.z, a.w);
            o.y = min3f(a.z, a.w, b.x);
            o.z = min3f(a.w, b.x, b.y);
            o.w = min3f(b.x, b.y, b.z);
            mWS4[wWr] = o;
        }
        pf.x = INF; pf.y = INF; pf.z = INF; pf.w = INF;
        if (isL && i < TDZ + 3) {
            int z = z0 - 1 + i;
            if ((unsigned)z < D_DIM && lVal)
                pf = *(const float4*)(in + (size_t)z * HW + lOff);
        }
        __syncthreads();   // B2: mWS4 ready

        // minH + rolling D-min -> eroded slice (masked)
        if (isH) {
            float4 r0 = mWS4[hRd], r1 = mWS4[hRd + MW4], r2 = mWS4[hRd + 2 * MW4];
            float4 mC;
            mC.x = min3f(r0.x, r1.x, r2.x);
            mC.y = min3f(r0.y, r1.y, r2.y);
            mC.z = min3f(r0.z, r1.z, r2.z);
            mC.w = min3f(r0.w, r1.w, r2.w);
            if (i >= 2) {
                bool zp = (unsigned)(z0 - 3 + i) < D_DIM;
                float4 e;
                e.x = (zp && sp0) ? min3f(mP2.x, mP1.x, mC.x) : -INF;
                e.y = (zp && sp1) ? min3f(mP2.y, mP1.y, mC.y) : -INF;
                e.z = (zp && sp2) ? min3f(mP2.z, mP1.z, mC.z) : -INF;
                e.w = (zp && sp3) ? min3f(mP2.w, mP1.w, mC.w) : -INF;
                eT4[hWr] = e;
            }
            mP2 = mP1; mP1 = mC;
        }
        __syncthreads();   // B3: eT4 ready

        // max9 direct + rolling D-max + elementwise update
        if (isO) {
            float4 A0 = eT4[oRd],           B0 = eT4[oRd + 1];
            float4 A1 = eT4[oRd + MW4],     B1 = eT4[oRd + MW4 + 1];
            float4 A2 = eT4[oRd + 2 * MW4], B2 = eT4[oRd + 2 * MW4 + 1];
            float4 s0, s1, s2, xC;
            s0.x = max3f(A0.y, A0.z, A0.w); s0.y = max3f(A0.z, A0.w, B0.x);
            s0.z = max3f(A0.w, B0.x, B0.y); s0.w = max3f(B0.x, B0.y, B0.z);
            s1.x = max3f(A1.y, A1.z, A1.w); s1.y = max3f(A1.z, A1.w, B1.x);
            s1.z = max3f(A1.w, B1.x, B1.y); s1.w = max3f(B1.x, B1.y, B1.z);
            s2.x = max3f(A2.y, A2.z, A2.w); s2.y = max3f(A2.z, A2.w, B2.x);
            s2.z = max3f(A2.w, B2.x, B2.y); s2.w = max3f(B2.x, B2.y, B2.z);
            xC.x = max3f(s0.x, s1.x, s2.x);
            xC.y = max3f(s0.y, s1.y, s2.y);
            xC.z = max3f(s0.z, s1.z, s2.z);
            xC.w = max3f(s0.w, s1.w, s2.w);
            float4 ecB; ecB.x = A1.z; ecB.y = A1.w; ecB.z = B1.x; ecB.w = B1.y;
            float4 aCn = aS4[cur][oAc];

            if (i >= 4) {
                float4 dl;
                dl.x = leaky(acA.x - max3f(xP2.x, xP1.x, xC.x));
                dl.y = leaky(acA.y - max3f(xP2.y, xP1.y, xC.y));
                dl.z = leaky(acA.z - max3f(xP2.z, xP1.z, xC.z));
                dl.w = leaky(acA.w - max3f(xP2.w, xP1.w, xC.w));
                if (step < NUM_ITER) aout4[ob] = ecA;
                if (step == 0) {
                    sk4[ob] = dl;
                } else {
                    float4 gg = sk4[ob];
                    float4 up, gn;
                    up.x = leaky(dl.x - gg.x * dl.x); gn.x = gg.x + up.x;
                    up.y = leaky(dl.y - gg.y * dl.y); gn.y = gg.y + up.y;
                    up.z = leaky(dl.z - gg.z * dl.z); gn.z = gg.z + up.z;
                    up.w = leaky(dl.w - gg.w * dl.w); gn.w = gg.w + up.w;
                    sk4[ob] = gn;
                    if (step == 1)
                        lsum += fabsf(gn.x) + fabsf(gn.y) + fabsf(gn.z) + fabsf(gn.w);
                    else
                        lsum += fabsf(up.x) + fabsf(up.y) + fabsf(up.z) + fabsf(up.w);
                }
                ob += HW4;
            }
            xP2 = xP1; xP1 = xC;
            acA = acB; acB = aCn;
            ecA = ecB;
        }
    }

    // dn reduction: one double atomic per block
    if (step > 0) {
        #pragma unroll
        for (int off = 32; off > 0; off >>= 1)
            lsum += __shfl_down(lsum, off, 64);
        const int lane = t & 63, wid = t >> 6;
        if (lane == 0) wsum[wid] = lsum;
        __syncthreads();
        if (t == 0) {
            float b = wsum[0] + wsum[1] + wsum[2] + wsum[3];
            atomicAdd(&slots[step], (double)b);
        }
    }
}

extern "C" void kernel_launch(void* const* d_in, const int* in_sizes, int n_in,
                              void* d_out, int out_size, void* d_ws, size_t ws_size,
                              hipStream_t stream) {
    const float* img = (const float*)d_in[0];
    float* out = (float*)d_out;
    float* buf0 = (float*)d_ws;
    float* buf1 = buf0 + NTOT;
    double* slots = (double*)(buf1 + NTOT);

    init_slots<<<1, 64, 0, stream>>>(slots);

    dim3 grid(W_DIM / TW, H_DIM / TH, (D_DIM / TDZ) * NIMG);
    for (int s = 0; s <= NUM_ITER; ++s) {
        const float* ain = (s == 0) ? img : ((s & 1) ? buf0 : buf1);
        float* aout = (s & 1) ? buf1 : buf0;
        skel_step<<<grid, 256, 0, stream>>>(ain, aout, out, slots, s);
    }
}

// Round 5
// 582.729 us; speedup vs baseline: 1.0874x; 1.0874x over previous
//
#include <hip/hip_runtime.h>
#include <math.h>

#define D_DIM 128
#define H_DIM 256
#define W_DIM 256
#define HW (H_DIM * W_DIM)
#define HW4 (HW / 4)
#define NIMG 2
#define NPI (D_DIM * HW)
#define NTOT (NIMG * NPI)

#define TDZ 32
#define TH 8
#define TW 32

#define AW4 10        // aS row width in float4 (40 floats): gx = x0-4 .. x0+35
#define AH 12         // aS rows: gy = y0-2 .. y0+9
#define MW4 9         // eT logical row width in f4 (36 cols): col j -> gx = x0-2+j
#define MW4P 10       // eT padded row width
#define EH 10         // eT rows: gy = y0-1+mh

#define NLOAD (AH * AW4)     // 120
#define NERO  (EH * MW4)     // 90
#define NOUT  (TH * (TW/4))  // 64

#define NUM_ITER 20
#define STOP_THRESH 1e-4

__device__ __forceinline__ float min3f(float a, float b, float c) { return fminf(fminf(a, b), c); }
__device__ __forceinline__ float max3f(float a, float b, float c) { return fmaxf(fmaxf(a, b), c); }
__device__ __forceinline__ float leaky(float x) { return fmaxf(x, 0.01f * x); }

__global__ void init_slots(double* slots) {
    if (threadIdx.x < 32) slots[threadIdx.x] = 0.0;
}

// Roles (contiguous thread ranges -> lane-contiguous b128, conflict-free):
//   L (t in [0,120))   : stage input slice window into aS4 (ping-pong), prefetch next
//   E (t in [160,250)) : 6x b128 from aS4 -> vertical min3 -> sliding min3 -> roll
//                        D-min in regs -> masked eroded slice to eT4
//   O (t in [64,128))  : 6x b128 from eT4 -> vertical max3 -> sliding max3 -> roll
//                        D-max in regs -> delta/skel update, a_out = erosion center
__global__ __launch_bounds__(256) void skel_step(
    const float* __restrict__ a_in,
    float* __restrict__ a_out,
    float* __restrict__ skel,
    double* __restrict__ slots,
    int step)
{
    __shared__ float4 aS4[2][AH * AW4];    // 2 x 120
    __shared__ float4 eT4[EH * MW4P];      // 100 (padded rows)
    __shared__ int s_active;

    const int t = threadIdx.x;

    if (t == 0) {
        int act = 1;
        for (int j = 1; j < step; ++j)
            if (!(slots[j] >= STOP_THRESH * (double)NTOT)) { act = 0; break; }
        s_active = act;
    }
    __syncthreads();
    if (!s_active) return;

    const int bx = blockIdx.x, by = blockIdx.y;
    const int bz = blockIdx.z & 3, img = blockIdx.z >> 2;
    const int x0 = bx * TW, y0 = by * TH, z0 = bz * TDZ;

    const float* in = a_in + (size_t)img * NPI;
    float4* aout4 = (float4*)(a_out + (size_t)img * NPI);
    float4* sk4 = (float4*)(skel + (size_t)img * NPI);

    // ---- L role ----
    const bool isL = t < NLOAD;
    int lWr = 0, lOff = 0; bool lVal = false;
    {
        int lr = t / AW4, lc = t - lr * AW4;
        int gy = y0 - 2 + lr, gx = x0 - 4 + 4 * lc;
        lVal = ((unsigned)gy < H_DIM) && ((unsigned)gx <= (unsigned)(W_DIM - 4));
        lOff = gy * W_DIM + gx;
        lWr = lr * AW4 + lc;
    }

    // ---- E role ----
    const int et = t - 160;
    const bool isE = (unsigned)et < NERO;
    int eRd = 0, eWr = 0;
    bool sp0 = false, sp1 = false, sp2 = false, sp3 = false;
    {
        int q = isE ? et : 0;
        int mh = q / MW4, ej = q - mh * MW4;
        eRd = mh * AW4 + ej;
        eWr = mh * MW4P + ej;
        int gye = y0 - 1 + mh;
        bool gyok = (unsigned)gye < H_DIM;
        int gxb = x0 - 2 + 4 * ej;
        sp0 = gyok && ((unsigned)(gxb + 0) < W_DIM);
        sp1 = gyok && ((unsigned)(gxb + 1) < W_DIM);
        sp2 = gyok && ((unsigned)(gxb + 2) < W_DIM);
        sp3 = gyok && ((unsigned)(gxb + 3) < W_DIM);
    }

    // ---- O role ----
    const int ot = t - 64;
    const bool isO = (unsigned)ot < NOUT;
    int oRd = 0, oAc = 0;
    size_t ob = 0;
    {
        int q = isO ? ot : 0;
        int oh = q >> 3, wq = q & 7;
        oRd = oh * MW4P + wq;
        oAc = (oh + 2) * AW4 + wq + 1;
        ob = ((size_t)z0 * HW + (size_t)(y0 + oh) * W_DIM + (size_t)x0) / 4 + wq;
    }

    const float INF = INFINITY;
    float4 mP2 = make_float4(INF, INF, INF, INF), mP1 = mP2;
    float4 xP2 = make_float4(-INF, -INF, -INF, -INF), xP1 = xP2;
    float4 acA = make_float4(0, 0, 0, 0), acB = acA, ecA = acA;
    float lsum = 0.f;

    // initial prefetch: slice zl = z0-2
    float4 pf = make_float4(INF, INF, INF, INF);
    if (isL) {
        int z = z0 - 2;
        if ((unsigned)z < D_DIM && lVal)
            pf = *(const float4*)(in + (size_t)z * HW + lOff);
    }

    for (int i = 0; i < TDZ + 4; ++i) {
        const int cur = i & 1;

        if (isL) aS4[cur][lWr] = pf;
        __syncthreads();   // B1: aS4[cur] ready

        // issue next prefetch (hides HBM latency under E+O)
        pf.x = INF; pf.y = INF; pf.z = INF; pf.w = INF;
        if (isL && i < TDZ + 3) {
            int z = z0 - 1 + i;
            if ((unsigned)z < D_DIM && lVal)
                pf = *(const float4*)(in + (size_t)z * HW + lOff);
        }

        float4 aCn;
        if (isO) aCn = aS4[cur][oAc];

        const bool zp = (unsigned)(z0 - 3 + i) < D_DIM;   // erosion slice in volume?

        if (isE) {
            float4 a0 = aS4[cur][eRd],           b0 = aS4[cur][eRd + 1];
            float4 a1 = aS4[cur][eRd + AW4],     b1 = aS4[cur][eRd + AW4 + 1];
            float4 a2 = aS4[cur][eRd + 2 * AW4], b2 = aS4[cur][eRd + 2 * AW4 + 1];
            float4 va, vb, mC;
            va.x = min3f(a0.x, a1.x, a2.x);
            va.y = min3f(a0.y, a1.y, a2.y);
            va.z = min3f(a0.z, a1.z, a2.z);
            va.w = min3f(a0.w, a1.w, a2.w);
            vb.x = min3f(b0.x, b1.x, b2.x);
            vb.y = min3f(b0.y, b1.y, b2.y);
            vb.z = min3f(b0.z, b1.z, b2.z);
            mC.x = min3f(va.y, va.z, va.w);
            mC.y = min3f(va.z, va.w, vb.x);
            mC.z = min3f(va.w, vb.x, vb.y);
            mC.w = min3f(vb.x, vb.y, vb.z);
            if (i >= 2 && zp) {
                float4 e;
                e.x = sp0 ? min3f(mP2.x, mP1.x, mC.x) : -INF;
                e.y = sp1 ? min3f(mP2.y, mP1.y, mC.y) : -INF;
                e.z = sp2 ? min3f(mP2.z, mP1.z, mC.z) : -INF;
                e.w = sp3 ? min3f(mP2.w, mP1.w, mC.w) : -INF;
                eT4[eWr] = e;
            }
            mP2 = mP1; mP1 = mC;
        }
        __syncthreads();   // B2: eT4 ready

        if (isO) {
            float4 xC, ecB;
            if (i >= 2 && zp) {
                float4 A0 = eT4[oRd],            B0 = eT4[oRd + 1];
                float4 A1 = eT4[oRd + MW4P],     B1 = eT4[oRd + MW4P + 1];
                float4 A2 = eT4[oRd + 2 * MW4P], B2 = eT4[oRd + 2 * MW4P + 1];
                float4 va, vb;
                va.x = max3f(A0.x, A1.x, A2.x);
                va.y = max3f(A0.y, A1.y, A2.y);
                va.z = max3f(A0.z, A1.z, A2.z);
                va.w = max3f(A0.w, A1.w, A2.w);
                vb.x = max3f(B0.x, B1.x, B2.x);
                vb.y = max3f(B0.y, B1.y, B2.y);
                vb.z = max3f(B0.z, B1.z, B2.z);
                xC.x = max3f(va.y, va.z, va.w);
                xC.y = max3f(va.z, va.w, vb.x);
                xC.z = max3f(va.w, vb.x, vb.y);
                xC.w = max3f(vb.x, vb.y, vb.z);
                ecB.x = A1.z; ecB.y = A1.w; ecB.z = B1.x; ecB.w = B1.y;
            } else {
                xC = make_float4(-INF, -INF, -INF, -INF);
                ecB = xC;
            }

            if (i >= 4) {
                float4 dl;
                dl.x = leaky(acA.x - max3f(xP2.x, xP1.x, xC.x));
                dl.y = leaky(acA.y - max3f(xP2.y, xP1.y, xC.y));
                dl.z = leaky(acA.z - max3f(xP2.z, xP1.z, xC.z));
                dl.w = leaky(acA.w - max3f(xP2.w, xP1.w, xC.w));
                if (step < NUM_ITER) aout4[ob] = ecA;
                if (step == 0) {
                    sk4[ob] = dl;
                } else {
                    float4 gg = sk4[ob];
                    float4 up, gn;
                    up.x = leaky(dl.x - gg.x * dl.x); gn.x = gg.x + up.x;
                    up.y = leaky(dl.y - gg.y * dl.y); gn.y = gg.y + up.y;
                    up.z = leaky(dl.z - gg.z * dl.z); gn.z = gg.z + up.z;
                    up.w = leaky(dl.w - gg.w * dl.w); gn.w = gg.w + up.w;
                    sk4[ob] = gn;
                    if (step == 1)
                        lsum += fabsf(gn.x) + fabsf(gn.y) + fabsf(gn.z) + fabsf(gn.w);
                    else
                        lsum += fabsf(up.x) + fabsf(up.y) + fabsf(up.z) + fabsf(up.w);
                }
                ob += HW4;
            }
            xP2 = xP1; xP1 = xC;
            acA = acB; acB = aCn;
            ecA = ecB;
        }
    }

    // dn reduction: O role is exactly wave 1; reduce in-wave, one atomic per block
    if (step > 0 && isO) {
        #pragma unroll
        for (int off = 32; off > 0; off >>= 1)
            lsum += __shfl_down(lsum, off, 64);
        if (ot == 0) atomicAdd(&slots[step], (double)lsum);
    }
}

extern "C" void kernel_launch(void* const* d_in, const int* in_sizes, int n_in,
                              void* d_out, int out_size, void* d_ws, size_t ws_size,
                              hipStream_t stream) {
    const float* img = (const float*)d_in[0];
    float* out = (float*)d_out;
    float* buf0 = (float*)d_ws;
    float* buf1 = buf0 + NTOT;
    double* slots = (double*)(buf1 + NTOT);

    init_slots<<<1, 64, 0, stream>>>(slots);

    dim3 grid(W_DIM / TW, H_DIM / TH, (D_DIM / TDZ) * NIMG);
    for (int s = 0; s <= NUM_ITER; ++s) {
        const float* ain = (s == 0) ? img : ((s & 1) ? buf0 : buf1);
        float* aout = (s & 1) ? buf1 : buf0;
        skel_step<<<grid, 256, 0, stream>>>(ain, aout, out, slots, s);
    }
}

// Round 6
// 513.891 us; speedup vs baseline: 1.2330x; 1.1340x over previous
//
#include <hip/hip_runtime.h>
#include <math.h>

#define D_DIM 128
#define H_DIM 256
#define W_DIM 256
#define HW (H_DIM * W_DIM)
#define NIMG 2
#define NPI (D_DIM * HW)
#define NTOT (NIMG * NPI)

#define TDZ 32
#define TH 8
#define TW 32
#define FH 12      // aS rows: gy = y0-2 .. y0+9
#define FW 36      // aS cols: gx = x0-2 .. x0+33
#define MH 10      // eT rows: gy = y0-1 ..
#define MW 34      // eT cols: gx = x0-1 ..

#define NL2 (FH * (FW/2))   // 216 float2 load items

#define NUM_ITER 20
#define STOP_THRESH 1e-4

__device__ __forceinline__ float leaky(float x) { return fmaxf(x, 0.01f * x); }
__device__ __forceinline__ float min3f(float a, float b, float c) { return fminf(fminf(a, b), c); }
__device__ __forceinline__ float max3f(float a, float b, float c) { return fmaxf(fmaxf(a, b), c); }

__device__ __forceinline__ float min9(const float* s, int b) {
    float a = min3f(s[b], s[b + 1], s[b + 2]);
    float c = min3f(s[b + FW], s[b + FW + 1], s[b + FW + 2]);
    float d = min3f(s[b + 2 * FW], s[b + 2 * FW + 1], s[b + 2 * FW + 2]);
    return min3f(a, c, d);
}

__device__ __forceinline__ float max9(const float* s, int b) {
    float a = max3f(s[b], s[b + 1], s[b + 2]);
    float c = max3f(s[b + MW], s[b + MW + 1], s[b + MW + 2]);
    float d = max3f(s[b + 2 * MW], s[b + 2 * MW + 1], s[b + 2 * MW + 2]);
    return max3f(a, c, d);
}

__global__ void init_slots(double* slots) {
    if (threadIdx.x < 32) slots[threadIdx.x] = 0.0;
}

// R3 structure (all threads all stages, scalar LDS, 2 barriers) unrolled x2 in z:
// per loop pair: commit 2 slices -> bar -> minW x2 + eroded x2 -> bar -> max9 x2
// + 2 outputs.  2-slice-deep float2 global prefetch.
__global__ __launch_bounds__(256) void skel_step(
    const float* __restrict__ a_in,
    float* __restrict__ a_out,
    float* __restrict__ skel,
    double* __restrict__ slots,
    int step)
{
    __shared__ float aSA[FH * FW];   // slice i0 window
    __shared__ float aSB[FH * FW];   // slice i1 window
    __shared__ float eTA[MH * MW];   // eroded slice (from i0), masked
    __shared__ float eTB[MH * MW];   // eroded slice (from i1), masked
    __shared__ float wsum[4];
    __shared__ int s_active;

    const int t = threadIdx.x;

    if (t == 0) {
        int act = 1;
        for (int j = 1; j < step; ++j)
            if (!(slots[j] >= STOP_THRESH * (double)NTOT)) { act = 0; break; }
        s_active = act;
    }
    __syncthreads();
    if (!s_active) return;

    const int bx = blockIdx.x, by = blockIdx.y;
    const int bz = blockIdx.z & 3, img = blockIdx.z >> 2;
    const int x0 = bx * TW, y0 = by * TH, z0 = bz * TDZ;

    const float* in = a_in + (size_t)img * NPI;
    float* aout = a_out + (size_t)img * NPI;
    float* sk = skel + (size_t)img * NPI;

    // ---- load role: one float2 per thread (t < 216), lane-linear chunks ----
    const bool isL = t < NL2;
    int lOff = 0, lWr = 0; bool lVal = false;
    {
        int q = isL ? t : 0;
        int lr = q / (FW / 2), lc = q - lr * (FW / 2);
        int gy = y0 - 2 + lr, gx = x0 - 2 + 2 * lc;
        lVal = isL && ((unsigned)gy < H_DIM) && (gx >= 0) && (gx <= W_DIM - 2);
        lOff = gy * W_DIM + gx;
        lWr = lr * FW + 2 * lc;
    }

    // ---- min role: items t and t+256 in the 10x34 grid ----
    const int m0 = t, m1 = t + 256;
    const bool m1v = (m1 < MH * MW);
    int ma0, ma1; bool e0v, e1v;
    {
        int mh0 = m0 / MW, mw0 = m0 - mh0 * MW;
        int mh1 = m1v ? m1 / MW : 0, mw1 = m1v ? m1 - (m1 / MW) * MW : 0;
        ma0 = mh0 * FW + mw0;
        ma1 = mh1 * FW + mw1;
        e0v = ((unsigned)(y0 - 1 + mh0) < H_DIM) & ((unsigned)(x0 - 1 + mw0) < W_DIM);
        e1v = m1v && ((unsigned)(y0 - 1 + mh1) < H_DIM) & ((unsigned)(x0 - 1 + mw1) < W_DIM);
    }

    // ---- out role: every thread owns one (oh,ow) column ----
    const int oh = t >> 5, ow = t & 31;
    const int xb = oh * MW + ow;
    const int aCenter = (oh + 2) * FW + (ow + 2);
    const int eCenter = (oh + 1) * MW + (ow + 1);
    size_t cgi = ((size_t)z0 * H_DIM + (y0 + oh)) * W_DIM + (x0 + ow);

    const float INF = INFINITY;

    // rolling registers
    float mP2 = INF, mP1 = INF, n1P2 = INF, n1P1 = INF;
    float xP2 = -INF, xP1 = -INF;
    float acP2 = 0.f, acP1 = 0.f, ecP = 0.f;
    float lsum = 0.f;

    // prefetch: cA = slices (0,1) [zl = z0-2, z0-1], fB = slices (2,3)
    float2 cA0, cA1, fB0, fB1;
    {
        float2 inf2 = make_float2(INF, INF);
        cA0 = inf2; cA1 = inf2; fB0 = inf2; fB1 = inf2;
        if (lVal) {
            int z;
            z = z0 - 2; if ((unsigned)z < D_DIM) cA0 = *(const float2*)(in + (size_t)z * HW + lOff);
            z = z0 - 1; if ((unsigned)z < D_DIM) cA1 = *(const float2*)(in + (size_t)z * HW + lOff);
            z = z0 + 0; if ((unsigned)z < D_DIM) fB0 = *(const float2*)(in + (size_t)z * HW + lOff);
            z = z0 + 1; if ((unsigned)z < D_DIM) fB1 = *(const float2*)(in + (size_t)z * HW + lOff);
        }
    }

    for (int k = 0; k < (TDZ + 4) / 2; ++k) {
        const int i0 = 2 * k, i1 = 2 * k + 1;

        // commit both slices; advance prefetch pipeline
        if (isL) {
            *(float2*)&aSA[lWr] = cA0;
            *(float2*)&aSB[lWr] = cA1;
        }
        cA0 = fB0; cA1 = fB1;
        {
            float2 inf2 = make_float2(INF, INF);
            fB0 = inf2; fB1 = inf2;
            if (k < (TDZ + 4) / 2 - 2 && lVal) {
                int z;
                z = z0 + 2 + 2 * k; if ((unsigned)z < D_DIM) fB0 = *(const float2*)(in + (size_t)z * HW + lOff);
                z = z0 + 3 + 2 * k; if ((unsigned)z < D_DIM) fB1 = *(const float2*)(in + (size_t)z * HW + lOff);
            }
        }
        __syncthreads();   // B1: aSA/aSB ready

        // stage 2: minW(H) for both slices; eroded slices -> LDS
        float mC0 = min9(aSA, ma0);
        float mC1 = min9(aSB, ma0);
        float n1C0 = 0.f, n1C1 = 0.f;
        if (m1v) { n1C0 = min9(aSA, ma1); n1C1 = min9(aSB, ma1); }
        float acC0 = aSA[aCenter];
        float acC1 = aSB[aCenter];

        const bool zp0 = (unsigned)(z0 - 3 + i0) < D_DIM;
        const bool zp1 = (unsigned)(z0 - 3 + i1) < D_DIM;
        if (i0 >= 2) {
            if (zp0) {
                eTA[m0] = e0v ? min3f(mP2, mP1, mC0) : -INF;
                if (m1v) eTA[m1] = e1v ? min3f(n1P2, n1P1, n1C0) : -INF;
            }
            if (zp1) {
                eTB[m0] = e0v ? min3f(mP1, mC0, mC1) : -INF;
                if (m1v) eTB[m1] = e1v ? min3f(n1P1, n1C0, n1C1) : -INF;
            }
        }
        mP2 = mC0; mP1 = mC1; n1P2 = n1C0; n1P1 = n1C1;
        __syncthreads();   // B2: eTA/eTB ready

        // stage 3: max9 for both slices; two outputs
        float xC0, xC1, ec0, ec1;
        if (i0 >= 2 && zp0) { xC0 = max9(eTA, xb); ec0 = eTA[eCenter]; }
        else { xC0 = -INF; ec0 = -INF; }
        if (i0 >= 2 && zp1) { xC1 = max9(eTB, xb); ec1 = eTB[eCenter]; }
        else { xC1 = -INF; ec1 = -INF; }

        if (i0 >= 4) {
            // output for slice i0 (depth z0-4+i0)
            {
                float dmax = max3f(xP2, xP1, xC0);
                float dl = leaky(acP2 - dmax);
                if (step < NUM_ITER) aout[cgi] = ecP;
                if (step == 0) {
                    sk[cgi] = dl;
                } else {
                    float g = sk[cgi];
                    float up = leaky(dl - g * dl);
                    float gn = g + up;
                    sk[cgi] = gn;
                    lsum += (step == 1) ? fabsf(gn) : fabsf(up);
                }
                cgi += HW;
            }
            // output for slice i1
            {
                float dmax = max3f(xP1, xC0, xC1);
                float dl = leaky(acP1 - dmax);
                if (step < NUM_ITER) aout[cgi] = ec0;
                if (step == 0) {
                    sk[cgi] = dl;
                } else {
                    float g = sk[cgi];
                    float up = leaky(dl - g * dl);
                    float gn = g + up;
                    sk[cgi] = gn;
                    lsum += (step == 1) ? fabsf(gn) : fabsf(up);
                }
                cgi += HW;
            }
        }
        xP2 = xC0; xP1 = xC1;
        acP2 = acC0; acP1 = acC1;
        ecP = ec1;
    }

    // dn reduction: one double atomic per block
    if (step > 0) {
        #pragma unroll
        for (int off = 32; off > 0; off >>= 1)
            lsum += __shfl_down(lsum, off, 64);
        const int lane = t & 63, wid = t >> 6;
        if (lane == 0) wsum[wid] = lsum;
        __syncthreads();
        if (t == 0) {
            float b = wsum[0] + wsum[1] + wsum[2] + wsum[3];
            atomicAdd(&slots[step], (double)b);
        }
    }
}

extern "C" void kernel_launch(void* const* d_in, const int* in_sizes, int n_in,
                              void* d_out, int out_size, void* d_ws, size_t ws_size,
                              hipStream_t stream) {
    const float* img = (const float*)d_in[0];
    float* out = (float*)d_out;
    float* buf0 = (float*)d_ws;
    float* buf1 = buf0 + NTOT;
    double* slots = (double*)(buf1 + NTOT);

    init_slots<<<1, 64, 0, stream>>>(slots);

    dim3 grid(W_DIM / TW, H_DIM / TH, (D_DIM / TDZ) * NIMG);
    for (int s = 0; s <= NUM_ITER; ++s) {
        const float* ain = (s == 0) ? img : ((s & 1) ? buf0 : buf1);
        float* aout = (s & 1) ? buf1 : buf0;
        skel_step<<<grid, 256, 0, stream>>>(ain, aout, out, slots, s);
    }
}

// Round 7
// 419.492 us; speedup vs baseline: 1.5105x; 1.2250x over previous
//
#include <hip/hip_runtime.h>
#include <math.h>

#define D_DIM 128
#define H_DIM 256
#define W_DIM 256
#define HW (H_DIM * W_DIM)
#define HW4 (HW / 4)
#define NIMG 2
#define NPI (D_DIM * HW)
#define NTOT (NIMG * NPI)

#define TDZ 16
#define TH 16
#define TW 64

#define AW4 18   // aS chunks/row: chunk c -> gx = x0-4+4c  (x0-4 .. x0+67)
#define AH 20    // aS rows: gy = y0-2 .. y0+17
#define EW4 17   // eT chunks/row: chunk c -> gx = x0-2+4c  (x0-2 .. x0+65)
#define EH 18    // eT rows: gy = y0-1 .. y0+16

#define NLOAD (AH * AW4)      // 360
#define NERO  (EH * EW4)      // 306
#define NOUT  (TH * (TW/4))   // 256

#define NUM_ITER 20
#define STOP_THRESH 1e-4

__device__ __forceinline__ float min3f(float a, float b, float c) { return fminf(fminf(a, b), c); }
__device__ __forceinline__ float max3f(float a, float b, float c) { return fmaxf(fmaxf(a, b), c); }
__device__ __forceinline__ float leaky(float x) { return fmaxf(x, 0.01f * x); }

__global__ void init_slots(double* slots) {
    if (threadIdx.x < 32) slots[threadIdx.x] = 0.0;
}

// f4-granular rolling-slice fused step; ALL threads active in every stage:
//   load:  360 f4 items (t, t+256 for t<104)
//   erode: 306 items (t, t+256 for t<50): 6x b128 -> vert min3 -> sliding min3,
//          rolling D-min regs -> masked eroded slice to eT4
//   out:   256 items (t): 6x b128 -> vert max3 -> sliding max3, rolling D-max,
//          delta/skel update; a_out = erosion centers (free from same reads)
__global__ __launch_bounds__(256) void skel_step(
    const float* __restrict__ a_in,
    float* __restrict__ a_out,
    float* __restrict__ skel,
    double* __restrict__ slots,
    int step)
{
    __shared__ float4 aS4[2][NLOAD];   // 11520 B
    __shared__ float4 eT4[NERO];       // 4896 B
    __shared__ float wsum[4];
    __shared__ int s_active;

    const int t = threadIdx.x;

    if (t == 0) {
        int act = 1;
        for (int j = 1; j < step; ++j)
            if (!(slots[j] >= STOP_THRESH * (double)NTOT)) { act = 0; break; }
        s_active = act;
    }
    __syncthreads();
    if (!s_active) return;

    const int bx = blockIdx.x, by = blockIdx.y;
    const int bz = blockIdx.z & 7, img = blockIdx.z >> 3;
    const int x0 = bx * TW, y0 = by * TH, z0 = bz * TDZ;

    const float* in = a_in + (size_t)img * NPI;
    float4* aout4 = (float4*)(a_out + (size_t)img * NPI);
    float4* sk4 = (float4*)(skel + (size_t)img * NPI);

    // ---- load items ----
    int lOff0, lOff1 = 0; bool lVal0, lVal1 = false;
    {
        int lr = t / AW4, lc = t - lr * AW4;
        int gy = y0 - 2 + lr, gx = x0 - 4 + 4 * lc;
        lVal0 = ((unsigned)gy < H_DIM) && ((unsigned)gx <= (unsigned)(W_DIM - 4));
        lOff0 = gy * W_DIM + gx;
    }
    const bool hasL1 = t < (NLOAD - 256);   // t < 104
    if (hasL1) {
        int q = t + 256;
        int lr = q / AW4, lc = q - lr * AW4;
        int gy = y0 - 2 + lr, gx = x0 - 4 + 4 * lc;
        lVal1 = ((unsigned)gy < H_DIM) && ((unsigned)gx <= (unsigned)(W_DIM - 4));
        lOff1 = gy * W_DIM + gx;
    }

    // ---- erode items ----
    int eRd0; bool sA0, sB0, sC0, sD0;
    {
        int mh = t / EW4, ej = t - mh * EW4;
        eRd0 = mh * AW4 + ej;
        int gy = y0 - 1 + mh;
        bool gok = (unsigned)gy < H_DIM;
        int gxb = x0 - 2 + 4 * ej;
        sA0 = gok && ((unsigned)(gxb + 0) < W_DIM);
        sB0 = gok && ((unsigned)(gxb + 1) < W_DIM);
        sC0 = gok && ((unsigned)(gxb + 2) < W_DIM);
        sD0 = gok && ((unsigned)(gxb + 3) < W_DIM);
    }
    const bool hasE1 = t < (NERO - 256);    // t < 50
    int eRd1 = 0; bool sA1 = false, sB1 = false, sC1 = false, sD1 = false;
    if (hasE1) {
        int q = t + 256;
        int mh = q / EW4, ej = q - mh * EW4;
        eRd1 = mh * AW4 + ej;
        int gy = y0 - 1 + mh;
        bool gok = (unsigned)gy < H_DIM;
        int gxb = x0 - 2 + 4 * ej;
        sA1 = gok && ((unsigned)(gxb + 0) < W_DIM);
        sB1 = gok && ((unsigned)(gxb + 1) < W_DIM);
        sC1 = gok && ((unsigned)(gxb + 2) < W_DIM);
        sD1 = gok && ((unsigned)(gxb + 3) < W_DIM);
    }

    // ---- out item ----
    const int oh = t >> 4, wq = t & 15;
    const int oRd = oh * EW4 + wq;
    const int oAc = (oh + 2) * AW4 + wq + 1;
    size_t ob = ((size_t)z0 * HW + (size_t)(y0 + oh) * W_DIM + (size_t)x0) / 4 + wq;

    const float INF = INFINITY;
    const float4 inf4 = make_float4(INF, INF, INF, INF);
    const float4 ninf4 = make_float4(-INF, -INF, -INF, -INF);
    float4 m0P2 = inf4, m0P1 = inf4, m1P2 = inf4, m1P1 = inf4;
    float4 xP2 = ninf4, xP1 = ninf4;
    float4 acA = make_float4(0, 0, 0, 0), acB = acA, ecA = acA;
    float lsum = 0.f;

    // initial prefetch: slice zl = z0-2
    float4 pf0 = inf4, pf1 = inf4;
    {
        int z = z0 - 2;
        if ((unsigned)z < D_DIM) {
            const float* p = in + (size_t)z * HW;
            if (lVal0) pf0 = *(const float4*)(p + lOff0);
            if (lVal1) pf1 = *(const float4*)(p + lOff1);
        }
    }

    for (int i = 0; i < TDZ + 4; ++i) {
        const int cur = i & 1;

        aS4[cur][t] = pf0;
        if (hasL1) aS4[cur][t + 256] = pf1;
        __syncthreads();   // B1: aS4[cur] ready

        // next prefetch (hides HBM latency under erode+out)
        pf0 = inf4; pf1 = inf4;
        {
            int z = z0 - 1 + i;
            if (i < TDZ + 3 && (unsigned)z < D_DIM) {
                const float* p = in + (size_t)z * HW;
                if (lVal0) pf0 = *(const float4*)(p + lOff0);
                if (lVal1) pf1 = *(const float4*)(p + lOff1);
            }
        }

        const float4 aCn = aS4[cur][oAc];
        const bool zp = (unsigned)(z0 - 3 + i) < D_DIM;   // erosion slice in volume?

        // ---- erode item 0 ----
        {
            const float4* s = aS4[cur];
            float4 a0 = s[eRd0],           b0 = s[eRd0 + 1];
            float4 a1 = s[eRd0 + AW4],     b1 = s[eRd0 + AW4 + 1];
            float4 a2 = s[eRd0 + 2 * AW4], b2 = s[eRd0 + 2 * AW4 + 1];
            float4 va, vb, mC;
            va.x = min3f(a0.x, a1.x, a2.x);
            va.y = min3f(a0.y, a1.y, a2.y);
            va.z = min3f(a0.z, a1.z, a2.z);
            va.w = min3f(a0.w, a1.w, a2.w);
            vb.x = min3f(b0.x, b1.x, b2.x);
            vb.y = min3f(b0.y, b1.y, b2.y);
            vb.z = min3f(b0.z, b1.z, b2.z);
            mC.x = min3f(va.y, va.z, va.w);
            mC.y = min3f(va.z, va.w, vb.x);
            mC.z = min3f(va.w, vb.x, vb.y);
            mC.w = min3f(vb.x, vb.y, vb.z);
            if (i >= 2 && zp) {
                float4 e;
                e.x = sA0 ? min3f(m0P2.x, m0P1.x, mC.x) : -INF;
                e.y = sB0 ? min3f(m0P2.y, m0P1.y, mC.y) : -INF;
                e.z = sC0 ? min3f(m0P2.z, m0P1.z, mC.z) : -INF;
                e.w = sD0 ? min3f(m0P2.w, m0P1.w, mC.w) : -INF;
                eT4[t] = e;
            }
            m0P2 = m0P1; m0P1 = mC;
        }
        // ---- erode item 1 ----
        if (hasE1) {
            const float4* s = aS4[cur];
            float4 a0 = s[eRd1],           b0 = s[eRd1 + 1];
            float4 a1 = s[eRd1 + AW4],     b1 = s[eRd1 + AW4 + 1];
            float4 a2 = s[eRd1 + 2 * AW4], b2 = s[eRd1 + 2 * AW4 + 1];
            float4 va, vb, mC;
            va.x = min3f(a0.x, a1.x, a2.x);
            va.y = min3f(a0.y, a1.y, a2.y);
            va.z = min3f(a0.z, a1.z, a2.z);
            va.w = min3f(a0.w, a1.w, a2.w);
            vb.x = min3f(b0.x, b1.x, b2.x);
            vb.y = min3f(b0.y, b1.y, b2.y);
            vb.z = min3f(b0.z, b1.z, b2.z);
            mC.x = min3f(va.y, va.z, va.w);
            mC.y = min3f(va.z, va.w, vb.x);
            mC.z = min3f(va.w, vb.x, vb.y);
            mC.w = min3f(vb.x, vb.y, vb.z);
            if (i >= 2 && zp) {
                float4 e;
                e.x = sA1 ? min3f(m1P2.x, m1P1.x, mC.x) : -INF;
                e.y = sB1 ? min3f(m1P2.y, m1P1.y, mC.y) : -INF;
                e.z = sC1 ? min3f(m1P2.z, m1P1.z, mC.z) : -INF;
                e.w = sD1 ? min3f(m1P2.w, m1P1.w, mC.w) : -INF;
                eT4[t + 256] = e;
            }
            m1P2 = m1P1; m1P1 = mC;
        }
        __syncthreads();   // B2: eT4 ready

        // ---- out ----
        {
            float4 xC, ecB;
            if (i >= 2 && zp) {
                float4 A0 = eT4[oRd],           B0 = eT4[oRd + 1];
                float4 A1 = eT4[oRd + EW4],     B1 = eT4[oRd + EW4 + 1];
                float4 A2 = eT4[oRd + 2 * EW4], B2 = eT4[oRd + 2 * EW4 + 1];
                float4 va, vb;
                va.x = max3f(A0.x, A1.x, A2.x);
                va.y = max3f(A0.y, A1.y, A2.y);
                va.z = max3f(A0.z, A1.z, A2.z);
                va.w = max3f(A0.w, A1.w, A2.w);
                vb.x = max3f(B0.x, B1.x, B2.x);
                vb.y = max3f(B0.y, B1.y, B2.y);
                vb.z = max3f(B0.z, B1.z, B2.z);
                xC.x = max3f(va.y, va.z, va.w);
                xC.y = max3f(va.z, va.w, vb.x);
                xC.z = max3f(va.w, vb.x, vb.y);
                xC.w = max3f(vb.x, vb.y, vb.z);
                ecB.x = A1.z; ecB.y = A1.w; ecB.z = B1.x; ecB.w = B1.y;
            } else {
                xC = ninf4; ecB = ninf4;
            }

            if (i >= 4) {
                float4 dl;
                dl.x = leaky(acA.x - max3f(xP2.x, xP1.x, xC.x));
                dl.y = leaky(acA.y - max3f(xP2.y, xP1.y, xC.y));
                dl.z = leaky(acA.z - max3f(xP2.z, xP1.z, xC.z));
                dl.w = leaky(acA.w - max3f(xP2.w, xP1.w, xC.w));
                if (step < NUM_ITER) aout4[ob] = ecA;
                if (step == 0) {
                    sk4[ob] = dl;
                } else {
                    float4 gg = sk4[ob];
                    float4 up, gn;
                    up.x = leaky(dl.x - gg.x * dl.x); gn.x = gg.x + up.x;
                    up.y = leaky(dl.y - gg.y * dl.y); gn.y = gg.y + up.y;
                    up.z = leaky(dl.z - gg.z * dl.z); gn.z = gg.z + up.z;
                    up.w = leaky(dl.w - gg.w * dl.w); gn.w = gg.w + up.w;
                    sk4[ob] = gn;
                    if (step == 1)
                        lsum += fabsf(gn.x) + fabsf(gn.y) + fabsf(gn.z) + fabsf(gn.w);
                    else
                        lsum += fabsf(up.x) + fabsf(up.y) + fabsf(up.z) + fabsf(up.w);
                }
                ob += HW4;
            }
            xP2 = xP1; xP1 = xC;
            acA = acB; acB = aCn;
            ecA = ecB;
        }
    }

    // dn reduction: one double atomic per block
    if (step > 0) {
        #pragma unroll
        for (int off = 32; off > 0; off >>= 1)
            lsum += __shfl_down(lsum, off, 64);
        const int lane = t & 63, wid = t >> 6;
        if (lane == 0) wsum[wid] = lsum;
        __syncthreads();
        if (t == 0) {
            float b = wsum[0] + wsum[1] + wsum[2] + wsum[3];
            atomicAdd(&slots[step], (double)b);
        }
    }
}

extern "C" void kernel_launch(void* const* d_in, const int* in_sizes, int n_in,
                              void* d_out, int out_size, void* d_ws, size_t ws_size,
                              hipStream_t stream) {
    const float* img = (const float*)d_in[0];
    float* out = (float*)d_out;
    float* buf0 = (float*)d_ws;
    float* buf1 = buf0 + NTOT;
    double* slots = (double*)(buf1 + NTOT);

    init_slots<<<1, 64, 0, stream>>>(slots);

    dim3 grid(W_DIM / TW, H_DIM / TH, (D_DIM / TDZ) * NIMG);
    for (int s = 0; s <= NUM_ITER; ++s) {
        const float* ain = (s == 0) ? img : ((s & 1) ? buf0 : buf1);
        float* aout = (s & 1) ? buf1 : buf0;
        skel_step<<<grid, 256, 0, stream>>>(ain, aout, out, slots, s);
    }
}